// Round 10
// baseline (13366.829 us; speedup 1.0000x reference)
//
#include <hip/hip_runtime.h>
#include <hip/hip_bf16.h>
#include <math.h>

#define B_ 128
#define T_ 2048
#define D_ 256
#define U_ 512
#define G4_ 2048
#define KT_ 768            // 512 (recurrent) + 256 (input) k-rows, transposed
#define ALPHA_ 0.001f

#define NGROUP 8           // batch groups (one per XCD under round-robin)
#define GB 16              // samples per group
#define NSLICE 32          // u-slices per group
#define SU 16              // u per slice
#define NWG (NGROUP*NSLICE) // 256  (1 WG/CU, fully resident)
#define NTH 256
#define BU (B_*U_)

typedef __attribute__((ext_vector_type(8))) short bf16x8;
typedef __attribute__((ext_vector_type(4))) float f32x4;
typedef __attribute__((ext_vector_type(4))) int i32x4;
typedef __attribute__((ext_vector_type(2))) int i32x2;
typedef __attribute__((ext_vector_type(4))) unsigned short us4;

// workspace layout (bytes)
#define OFF_WT 0                        // transposed bf16 weights: 3 MiB
#define OFF_H32 (G4_*KT_*2)             // 2 tagged h buffers: 2*BU*4 = 512 KiB
#define OFF_CNT (OFF_H32 + 2*BU*4)      // 8 group counters, 256B apart
#define CNT_DW (NGROUP*64)

__device__ __forceinline__ unsigned short f2b(float f) {
  unsigned u = __builtin_bit_cast(unsigned, f);
  u += 0x7fffu + ((u >> 16) & 1u);   // round-to-nearest-even bf16
  return (unsigned short)(u >> 16);
}

__device__ __forceinline__ float ftanh(float v) {
  v = fminf(fmaxf(v, -15.f), 15.f);
  float e = __expf(2.f * v);
  return (e - 1.f) * __builtin_amdgcn_rcpf(e + 1.f);
}

__global__ void prep_kernel(const float* __restrict__ kern,
                            const float* __restrict__ rker,
                            const float* __restrict__ h0,
                            unsigned short* __restrict__ wt,
                            unsigned* __restrict__ h32,
                            unsigned* __restrict__ cnt) {
  int idx = blockIdx.x * blockDim.x + threadIdx.x;
  int stride = gridDim.x * blockDim.x;
  for (int i = idx; i < G4_ * KT_; i += stride) {
    int col = i / KT_, k = i - col * KT_;
    float v = (k < U_) ? rker[(size_t)k * G4_ + col]
                       : kern[(size_t)(k - U_) * G4_ + col];
    wt[i] = f2b(v);
  }
  for (int i = idx; i < BU; i += stride) {
    h32[i] = ((unsigned)f2b(h0[i]) << 16);   // tag 0 = state entering step 0
    h32[BU + i] = 0xFFFFu;                   // impossible tag (kills stale runs)
  }
  for (int i = idx; i < CNT_DW; i += stride) cnt[i] = 0u;
}

// coalesced bulk h load: per instruction, 64 lanes x 16B = 1KB contiguous
#define LOAD8_G(SC)                                                    \
  asm volatile(                                                        \
      "global_load_dwordx4 %0, %8, off " SC "\n\t"                     \
      "global_load_dwordx4 %1, %8, off offset:1024 " SC "\n\t"         \
      "global_load_dwordx4 %2, %8, off offset:2048 " SC "\n\t"         \
      "global_load_dwordx4 %3, %8, off offset:3072 " SC "\n\t"         \
      "global_load_dwordx4 %4, %9, off " SC "\n\t"                     \
      "global_load_dwordx4 %5, %9, off offset:1024 " SC "\n\t"         \
      "global_load_dwordx4 %6, %9, off offset:2048 " SC "\n\t"         \
      "global_load_dwordx4 %7, %9, off offset:3072 " SC                \
      : "=&v"(v0), "=&v"(v1), "=&v"(v2), "=&v"(v3),                    \
        "=&v"(v4), "=&v"(v5), "=&v"(v6), "=&v"(v7)                     \
      : "v"(ppoll), "v"(ppoll2));                                      \
  __builtin_amdgcn_sched_barrier(0)

#define LOAD8F() LOAD8_G("sc0")          // L2-scope (same-XCD fast path)
#define LOAD8S() LOAD8_G("sc0 sc1")      // L3-scope (proven-safe path, R8)

#define FENCE8()                                                       \
  asm volatile("s_waitcnt vmcnt(0)"                                    \
      : "+v"(v0), "+v"(v1), "+v"(v2), "+v"(v3),                        \
        "+v"(v4), "+v"(v5), "+v"(v6), "+v"(v7));                       \
  __builtin_amdgcn_sched_barrier(0)

#define CKV(vv) ((((unsigned)(vv)[0] ^ tgv) & 0xffffu) |               \
                 (((unsigned)(vv)[1] ^ tgv) & 0xffffu) |               \
                 (((unsigned)(vv)[2] ^ tgv) & 0xffffu) |               \
                 (((unsigned)(vv)[3] ^ tgv) & 0xffffu))

#define PK(lo, hi) (int)(((unsigned)(hi) & 0xffff0000u) | ((unsigned)(lo) >> 16))

// strip tags from one 16B chunk -> 8B bf16 pair-write to swizzled LDS
// chunk k covers h[row = wave*4 + (k>>1)][u = (k&1)*256 + lane*4 .. +3]
#define PACK2(vv, k)                                                         \
  { const int r_ = 4 * wv + ((k) >> 1);                                      \
    const int ba_ = (r_ * 1024 + (((k) & 1) << 9) + 8 * ln) ^ ((r_ & 7) << 4); \
    i32x2 d_ = { PK((vv)[0], (vv)[1]), PK((vv)[2], (vv)[3]) };               \
    *(i32x2*)(hdst + ba_) = d_; }

__global__ __launch_bounds__(NTH, 1) void plstm_kernel(
    const float* __restrict__ x, const float* __restrict__ h0,
    const float* __restrict__ c0, const float* __restrict__ t0,
    const float* __restrict__ bias, const float* __restrict__ tg,
    const unsigned short* __restrict__ wt,
    unsigned* h32, unsigned* cnt, float* __restrict__ out) {
  const int wg = blockIdx.x;
  const int g = wg & 7, sl = wg >> 3;   // group == XCD (round-robin locality)
  const int b0 = g * GB, u0 = sl * SU;
  const int tid = threadIdx.x;
  const int wave = tid >> 6, lane = tid & 63;

  __shared__ unsigned short h_lds[2][GB * U_];   // 2 x 16 KiB, XOR-swizzled
  __shared__ unsigned short x_lds[2][GB * D_];   // 2 x 8 KiB
  __shared__ float z_lds[2][GB][68];             // 64 + pad
  __shared__ unsigned wgarr[4];                  // per-WG arrive slots

  // ---- weight fragments (transposed layout: contiguous 16B per frag) ----
  bf16x8 br[16], bx[8];
  {
    const int kr0 = (lane >> 4) * 8;
    const int col0 = wave * U_ + u0 + (lane & 15);
    const unsigned short* w0 = wt + (size_t)col0 * KT_;
#pragma unroll
    for (int kt = 0; kt < 16; ++kt) br[kt] = *(const bf16x8*)(w0 + kt * 32 + kr0);
#pragma unroll
    for (int kt = 0; kt < 8; ++kt)  bx[kt] = *(const bf16x8*)(w0 + U_ + kt * 32 + kr0);
  }
  const float bias_l = bias[wave * U_ + u0 + (lane & 15)];

  // ---- per-thread elementwise state: (sample srow, single u) ----
  const int srow = tid >> 4;
  const int j = tid & 15;
  const int bb = b0 + srow;
  const int uu = u0 + j;
  float c_st = c0[bb * U_ + uu];
  float h_st = h0[bb * U_ + uu];
  const float t_0 = t0[bb * U_ + uu];
  const float per = tg[uu];
  const float shf = tg[U_ + uu];
  const float ron = tg[2 * U_ + uu];

  const int arow = lane & 15;
  const int koff = (lane >> 4) * 16;
  const int swzA = (arow & 7) << 4;
  const int swzR = (srow & 7) << 4;
  const int wv = wave, ln = lane;

  auto stage_x = [&](int t, int buf) {
    const int f0 = j * 16;
    const float* xp = x + ((size_t)bb * T_ + t) * D_ + f0;
    char* base = (char*)&x_lds[buf][0];
#pragma unroll
    for (int q = 0; q < 4; ++q) {
      float4 v = *(const float4*)(xp + q * 4);
      us4 pk = { f2b(v.x), f2b(v.y), f2b(v.z), f2b(v.w) };
      *(us4*)(base + ((srow * 512 + (f0 + q * 4) * 2) ^ swzR)) = pk;
    }
  };

  stage_x(0, 0);
  stage_x(1, 1);
  if (tid < 4) wgarr[tid] = 0u;
  __syncthreads();   // covers prologue x staging + wgarr init

  // wave-linear bulk pointers: wave w covers group-slab bytes [w*8K,(w+1)*8K)
  const unsigned* gslab0 = h32 + (size_t)b0 * U_;
  const int poff = wave * 2048 + lane * 4;   // dwords
  unsigned* cnt_g = cnt + g * 64;

  int useL3 = 0;   // per-wave adaptive: 0 = try L2 (sc0), 1 = proven L3 path

  for (int step = 0; step < T_; ++step) {
    const int par = step & 1;

    // ---- (1) per-wave counter wait (uniform addr -> 1 txn per poll) ----
    // counter >= 32*step  <=>  all 32 WGs arrived for step-1 (h(step) stored)
    if (step > 0) {
      const unsigned tgt = 32u * (unsigned)step;
      while (__hip_atomic_load(cnt_g, __ATOMIC_RELAXED,
                               __HIP_MEMORY_SCOPE_AGENT) < tgt)
        __builtin_amdgcn_s_sleep(1);
    }

    // ---- (2) single fresh bulk h load, fired immediately on poll pass ----
    const unsigned* ppoll = gslab0 + (size_t)par * BU + poff;
    const unsigned* ppoll2 = ppoll + 1024;
    i32x4 v0, v1, v2, v3, v4, v5, v6, v7;
    if (useL3) { LOAD8S(); } else { LOAD8F(); }

    // ---- (3) time-gate coeff + x-partial GEMM in the load RTT shadow ----
    float kk;
    {
      float xx = t_0 + (float)(step + 1) - shf;
      float ph = (xx - per * floorf(xx / per)) / per;
      kk = (ph <= 0.5f * ron) ? (2.f * ph / ron)
         : ((ph <= ron) ? (2.f - 2.f * ph / ron) : (ALPHA_ * ph));
    }
    f32x4 aa = { bias_l, bias_l, bias_l, bias_l };
    f32x4 ab = { 0.f, 0.f, 0.f, 0.f };
    {
      // x_lds[par] written post-S1(step-2); separated by S2(step-2),S1(step-1) ✓
      const char* xb = (const char*)&x_lds[par][0];
#pragma unroll
      for (int kt = 0; kt < 8; ++kt) {
        bf16x8 a = *(const bf16x8*)(xb + ((arow * 512 + kt * 64 + koff) ^ swzA));
        if (kt & 1) ab = __builtin_amdgcn_mfma_f32_16x16x32_bf16(a, bx[kt], ab, 0, 0, 0);
        else        aa = __builtin_amdgcn_mfma_f32_16x16x32_bf16(a, bx[kt], aa, 0, 0, 0);
      }
    }

    // ---- (4) validate tags; stale -> bounded retries, then promote to L3 ----
    // Counter pass guarantees producers stored (sc0 sc1 -> L3). If L2 serves
    // stale lines systematically (sc1 stores bypass w/o invalidate), the sc0
    // path fails 8x and this wave permanently falls back to R8's proven path.
    const unsigned tgv = (unsigned)step;
    int fails = 0;
    FENCE8();
    for (;;) {
      unsigned bad = CKV(v0) | CKV(v1) | CKV(v2) | CKV(v3) |
                     CKV(v4) | CKV(v5) | CKV(v6) | CKV(v7);
      if (!bad) break;
      ++fails;
      __builtin_amdgcn_s_sleep(1);
      if (useL3 || fails >= 8) { LOAD8S(); } else { LOAD8F(); }
      FENCE8();
    }
    if (__any(fails >= 8)) useL3 = 1;   // wave-uniform promotion, sticky

    // ---- (5) strip tags -> swizzled h_lds[par] ----
    // WAR vs h-GEMM read(step-2, same parity): counter(step) pass => all WGs
    // past gates(step-1) ⊃ far past h-GEMM(step-2). ✓
    {
      char* hdst = (char*)&h_lds[par][0];
      PACK2(v0, 0); PACK2(v1, 1); PACK2(v2, 2); PACK2(v3, 3);
      PACK2(v4, 4); PACK2(v5, 5); PACK2(v6, 6); PACK2(v7, 7);
    }
    __syncthreads();   // S1: h_lds[par] ready

    // ---- (5.5) x prefetch for step+2: x_lds[par] dead after S1; loads
    // overlap h-GEMM below; LDS writes complete before S2; keeps the
    // stage_x vmcnt wait away from next step's poll entry. ----
    if (step + 2 < T_) stage_x(step + 2, par);

    // ---- (6) recurrent GEMM (2 interleaved acc chains) ----
    {
      const char* hbm = (const char*)&h_lds[par][0];
#pragma unroll
      for (int kt = 0; kt < 16; ++kt) {
        bf16x8 a = *(const bf16x8*)(hbm + ((arow * 1024 + kt * 64 + koff) ^ swzA));
        if (kt & 1) ab = __builtin_amdgcn_mfma_f32_16x16x32_bf16(a, br[kt], ab, 0, 0, 0);
        else        aa = __builtin_amdgcn_mfma_f32_16x16x32_bf16(a, br[kt], aa, 0, 0, 0);
      }
    }
    const f32x4 acc = aa + ab;

    // ---- (7) z exchange (C/D: col=lane&15, row=(lane>>4)*4+r) ----
#pragma unroll
    for (int r2 = 0; r2 < 4; ++r2)
      z_lds[par][(lane >> 4) * 4 + r2][wave * 16 + (lane & 15)] = acc[r2];
    __syncthreads();   // S2: z ready

    // ---- (8) gates: h path first -> tagged store ASAP, arrive, then tail ----
    float chat;
    {
      const float* zr = &z_lds[par][srow][0];
      const float zi = zr[j], zf = zr[16 + j], zc = zr[32 + j], zo = zr[48 + j];
      float ig = fminf(fmaxf(0.2f * zi + 0.5f, 0.f), 1.f);
      float fg = fminf(fmaxf(0.2f * zf + 0.5f, 0.f), 1.f);
      float og = fminf(fmaxf(0.2f * zo + 0.5f, 0.f), 1.f);
      chat = fg * c_st + ig * ftanh(zc);
      float hhat = og * ftanh(chat);
      h_st = kk * hhat + (1.f - kk) * h_st;
      unsigned hv = ((unsigned)f2b(h_st) << 16) | (unsigned)(step + 1);
      const unsigned* hp = h32 + (size_t)((step + 1) & 1) * BU + bb * U_ + uu;
      asm volatile("global_store_dword %0, %1, off sc0 sc1"
                   :: "v"(hp), "v"(hv) : "memory");
    }

    // ---- (9) barrier-free hierarchical arrive — NO drain (tags cover) ----
    // LDS round gives the h-stores a visibility head start (R9 lesson: this
    // delay is load-bearing) before the counter release fires.
    if (lane == 0) {
      unsigned old = atomicAdd(&wgarr[step & 3], 1u);  // LDS, per-wave arrive
      if (old == 3u) {                                  // 4th wave of this WG
        wgarr[step & 3] = 0u;
        atomicAdd(cnt_g, 1u);                           // agent scope (proven)
      }
    }

    // ---- (10) off-critical-path tail (VALU + cached store only) ----
    c_st = kk * chat + (1.f - kk) * c_st;
    out[((size_t)bb * T_ + step) * U_ + uu] = h_st;
  }
}

extern "C" void kernel_launch(void* const* d_in, const int* in_sizes, int n_in,
                              void* d_out, int out_size, void* d_ws,
                              size_t ws_size, hipStream_t stream) {
  const float* x    = (const float*)d_in[0];
  const float* h0   = (const float*)d_in[1];
  const float* c0   = (const float*)d_in[2];
  const float* t0   = (const float*)d_in[3];
  const float* kern = (const float*)d_in[4];
  const float* rker = (const float*)d_in[5];
  const float* bias = (const float*)d_in[6];
  const float* tg   = (const float*)d_in[7];
  float* out = (float*)d_out;

  char* ws = (char*)d_ws;
  unsigned short* wt = (unsigned short*)(ws + OFF_WT);
  unsigned* h32      = (unsigned*)(ws + OFF_H32);
  unsigned* cnt      = (unsigned*)(ws + OFF_CNT);

  prep_kernel<<<1024, 256, 0, stream>>>(kern, rker, h0, wt, h32, cnt);
  plstm_kernel<<<NWG, NTH, 0, stream>>>(x, h0, c0, t0, bias, tg, wt, h32,
                                        cnt, out);
}

// Round 11
// 12725.507 us; speedup vs baseline: 1.0504x; 1.0504x over previous
//
#include <hip/hip_runtime.h>
#include <hip/hip_bf16.h>
#include <math.h>

#define B_ 128
#define T_ 2048
#define D_ 256
#define U_ 512
#define G4_ 2048
#define KT_ 768            // 512 (recurrent) + 256 (input) k-rows, transposed
#define ALPHA_ 0.001f

#define NGROUP 8           // batch groups (one per XCD under round-robin)
#define GB 16              // samples per group
#define NSLICE 8           // u-slices per group
#define SU 64              // u per slice (16 per wave x 4 waves)
#define NWG (NGROUP*NSLICE) // 64
#define NTH 256
#define BU (B_*U_)

typedef __attribute__((ext_vector_type(8))) short bf16x8;
typedef __attribute__((ext_vector_type(4))) float f32x4;
typedef __attribute__((ext_vector_type(4))) int i32x4;
typedef __attribute__((ext_vector_type(2))) int i32x2;
typedef __attribute__((ext_vector_type(4))) unsigned short us4;

// workspace layout (bytes)
#define OFF_WT 0                        // transposed bf16 weights: 3 MiB
#define OFF_H32 (G4_*KT_*2)             // 2 tagged h buffers: 2*BU*4 = 512 KiB
#define OFF_CNT (OFF_H32 + 2*BU*4)      // 8 group counters, 256B apart
#define CNT_DW (NGROUP*64)

__device__ __forceinline__ unsigned short f2b(float f) {
  unsigned u = __builtin_bit_cast(unsigned, f);
  u += 0x7fffu + ((u >> 16) & 1u);   // round-to-nearest-even bf16
  return (unsigned short)(u >> 16);
}

__device__ __forceinline__ float ftanh(float v) {
  v = fminf(fmaxf(v, -15.f), 15.f);
  float e = __expf(2.f * v);
  return (e - 1.f) * __builtin_amdgcn_rcpf(e + 1.f);
}

__global__ void prep_kernel(const float* __restrict__ kern,
                            const float* __restrict__ rker,
                            const float* __restrict__ h0,
                            unsigned short* __restrict__ wt,
                            unsigned* __restrict__ h32,
                            unsigned* __restrict__ cnt) {
  int idx = blockIdx.x * blockDim.x + threadIdx.x;
  int stride = gridDim.x * blockDim.x;
  for (int i = idx; i < G4_ * KT_; i += stride) {
    int col = i / KT_, k = i - col * KT_;
    float v = (k < U_) ? rker[(size_t)k * G4_ + col]
                       : kern[(size_t)(k - U_) * G4_ + col];
    wt[i] = f2b(v);
  }
  for (int i = idx; i < BU; i += stride) {
    h32[i] = ((unsigned)f2b(h0[i]) << 16);   // tag 0 = state entering step 0
    h32[BU + i] = 0xFFFFu;                   // impossible tag (kills stale runs)
  }
  for (int i = idx; i < CNT_DW; i += stride) cnt[i] = 0u;
}

// coalesced bulk h load: per instruction, 64 lanes x 16B = 1KB contiguous
#define LOAD8()                                                        \
  asm volatile(                                                        \
      "global_load_dwordx4 %0, %8, off sc0 sc1\n\t"                    \
      "global_load_dwordx4 %1, %8, off offset:1024 sc0 sc1\n\t"        \
      "global_load_dwordx4 %2, %8, off offset:2048 sc0 sc1\n\t"        \
      "global_load_dwordx4 %3, %8, off offset:3072 sc0 sc1\n\t"        \
      "global_load_dwordx4 %4, %9, off sc0 sc1\n\t"                    \
      "global_load_dwordx4 %5, %9, off offset:1024 sc0 sc1\n\t"        \
      "global_load_dwordx4 %6, %9, off offset:2048 sc0 sc1\n\t"        \
      "global_load_dwordx4 %7, %9, off offset:3072 sc0 sc1"            \
      : "=&v"(v0), "=&v"(v1), "=&v"(v2), "=&v"(v3),                    \
        "=&v"(v4), "=&v"(v5), "=&v"(v6), "=&v"(v7)                     \
      : "v"(ppoll), "v"(ppoll2));                                      \
  __builtin_amdgcn_sched_barrier(0)

#define FENCE8()                                                       \
  asm volatile("s_waitcnt vmcnt(0)"                                    \
      : "+v"(v0), "+v"(v1), "+v"(v2), "+v"(v3),                        \
        "+v"(v4), "+v"(v5), "+v"(v6), "+v"(v7));                       \
  __builtin_amdgcn_sched_barrier(0)

#define CKV(vv) ((((unsigned)(vv)[0] ^ tgv) & 0xffffu) |               \
                 (((unsigned)(vv)[1] ^ tgv) & 0xffffu) |               \
                 (((unsigned)(vv)[2] ^ tgv) & 0xffffu) |               \
                 (((unsigned)(vv)[3] ^ tgv) & 0xffffu))

#define PK(lo, hi) (int)(((unsigned)(hi) & 0xffff0000u) | ((unsigned)(lo) >> 16))

// strip tags from one 16B chunk -> 8B bf16 pair-write to swizzled LDS
// chunk k covers h[row = wave*4 + (k>>1)][u = (k&1)*256 + lane*4 .. +3]
#define PACK2(vv, k)                                                         \
  { const int r_ = 4 * wv + ((k) >> 1);                                      \
    const int ba_ = (r_ * 1024 + (((k) & 1) << 9) + 8 * ln) ^ ((r_ & 7) << 4); \
    i32x2 d_ = { PK((vv)[0], (vv)[1]), PK((vv)[2], (vv)[3]) };               \
    *(i32x2*)(hdst + ba_) = d_; }

__global__ __launch_bounds__(NTH, 1) void plstm_kernel(
    const float* __restrict__ x, const float* __restrict__ h0,
    const float* __restrict__ c0, const float* __restrict__ t0,
    const float* __restrict__ bias, const float* __restrict__ tg,
    const unsigned short* __restrict__ wt,
    unsigned* h32, unsigned* cnt, float* __restrict__ out) {
  const int wg = blockIdx.x;
  const int g = wg & 7, sl = wg >> 3;   // group == XCD (round-robin locality)
  const int b0 = g * GB, u0 = sl * SU;
  const int tid = threadIdx.x;
  const int wave = tid >> 6, lane = tid & 63;

  __shared__ unsigned short h_lds[2][GB * U_];   // 2 x 16 KiB, XOR-swizzled
  __shared__ unsigned short x_lds[2][GB * D_];   // 2 x 8 KiB
  __shared__ unsigned wgarr[4];                  // per-WG arrive slots

  // ---- weight fragments: wave covers u [u0+16*wave, +16), ALL 4 gates ----
  // (4 gate-tiles share the A operand; thread's accs hold all 4 z's -> no
  //  z-exchange LDS round, no S2 barrier)
  bf16x8 br[4][16], bx[4][8];
  const int uw = u0 + wave * 16 + (lane & 15);   // this lane's u column
  {
    const int kr0 = (lane >> 4) * 8;
#pragma unroll
    for (int gq = 0; gq < 4; ++gq) {
      const unsigned short* w0 = wt + (size_t)(gq * U_ + uw) * KT_;
#pragma unroll
      for (int kt = 0; kt < 16; ++kt) br[gq][kt] = *(const bf16x8*)(w0 + kt * 32 + kr0);
#pragma unroll
      for (int kt = 0; kt < 8; ++kt)  bx[gq][kt] = *(const bf16x8*)(w0 + U_ + kt * 32 + kr0);
    }
  }
  const float bi_i = bias[0 * U_ + uw];
  const float bi_f = bias[1 * U_ + uw];
  const float bi_c = bias[2 * U_ + uw];
  const float bi_o = bias[3 * U_ + uw];

  // ---- per-thread elementwise state: 4 samples (C-layout rows) x 1 u ----
  // C/D layout: col = lane&15 (= uw), row = (lane>>4)*4 + r2
  const int r0 = (lane >> 4) * 4;
  float c_st[4], h_st[4], t_0[4];
#pragma unroll
  for (int r2 = 0; r2 < 4; ++r2) {
    const int bb = b0 + r0 + r2;
    c_st[r2] = c0[bb * U_ + uw];
    h_st[r2] = h0[bb * U_ + uw];
    t_0[r2] = t0[bb * U_ + uw];
  }
  const float per = tg[uw];
  const float shf = tg[U_ + uw];
  const float ron = tg[2 * U_ + uw];

  const int arow = lane & 15;
  const int koff = (lane >> 4) * 16;
  const int swzA = (arow & 7) << 4;
  const int wv = wave, ln = lane;

  // x staging: thread (srow, j16) loads 16 of sample srow's 256 features
  const int srow = tid >> 4;
  const int j16 = tid & 15;
  const int swzR = (srow & 7) << 4;
  auto stage_x = [&](int t, int buf) {
    const int f0 = j16 * 16;
    const float* xp = x + ((size_t)(b0 + srow) * T_ + t) * D_ + f0;
    char* base = (char*)&x_lds[buf][0];
#pragma unroll
    for (int q = 0; q < 4; ++q) {
      float4 v = *(const float4*)(xp + q * 4);
      us4 pk = { f2b(v.x), f2b(v.y), f2b(v.z), f2b(v.w) };
      *(us4*)(base + ((srow * 512 + (f0 + q * 4) * 2) ^ swzR)) = pk;
    }
  };

  stage_x(0, 0);
  stage_x(1, 1);
  if (tid < 4) wgarr[tid] = 0u;
  __syncthreads();   // covers prologue x staging + wgarr init

  // wave-linear bulk pointers: wave w covers group-slab bytes [w*8K,(w+1)*8K)
  const unsigned* gslab0 = h32 + (size_t)b0 * U_;
  const int poff = wave * 2048 + lane * 4;   // dwords
  unsigned* cnt_g = cnt + g * 64;

  for (int step = 0; step < T_; ++step) {
    const int par = step & 1;

    // ---- (1) per-wave counter wait: >= 8*step <=> all 8 WGs arrived ----
    if (step > 0) {
      const unsigned tgt = (unsigned)(NSLICE * step);
      while (__hip_atomic_load(cnt_g, __ATOMIC_RELAXED,
                               __HIP_MEMORY_SCOPE_AGENT) < tgt)
        __builtin_amdgcn_s_sleep(1);
    }

    // ---- (2) single fresh bulk h load, fired immediately on poll pass ----
    const unsigned* ppoll = gslab0 + (size_t)par * BU + poff;
    const unsigned* ppoll2 = ppoll + 1024;
    i32x4 v0, v1, v2, v3, v4, v5, v6, v7;
    LOAD8();

    // ---- (3) time-gate coeffs + x-partial GEMM in the load RTT shadow ----
    float kk[4];
#pragma unroll
    for (int r2 = 0; r2 < 4; ++r2) {
      float xx = t_0[r2] + (float)(step + 1) - shf;
      float ph = (xx - per * floorf(xx / per)) / per;
      kk[r2] = (ph <= 0.5f * ron) ? (2.f * ph / ron)
             : ((ph <= ron) ? (2.f - 2.f * ph / ron) : (ALPHA_ * ph));
    }
    f32x4 ai = { bi_i, bi_i, bi_i, bi_i };
    f32x4 af = { bi_f, bi_f, bi_f, bi_f };
    f32x4 ac = { bi_c, bi_c, bi_c, bi_c };
    f32x4 ao = { bi_o, bi_o, bi_o, bi_o };
    {
      // x_lds[par] written post-S1(step-2); S1(step-1) separates ✓
      const char* xb = (const char*)&x_lds[par][0];
#pragma unroll
      for (int kt = 0; kt < 8; ++kt) {
        bf16x8 a = *(const bf16x8*)(xb + ((arow * 512 + kt * 64 + koff) ^ swzA));
        ai = __builtin_amdgcn_mfma_f32_16x16x32_bf16(a, bx[0][kt], ai, 0, 0, 0);
        af = __builtin_amdgcn_mfma_f32_16x16x32_bf16(a, bx[1][kt], af, 0, 0, 0);
        ac = __builtin_amdgcn_mfma_f32_16x16x32_bf16(a, bx[2][kt], ac, 0, 0, 0);
        ao = __builtin_amdgcn_mfma_f32_16x16x32_bf16(a, bx[3][kt], ao, 0, 0, 0);
      }
    }

    // ---- (4) validate tags; stale (no-drain straggler) -> reload ----
    const unsigned tgv = (unsigned)step;
    FENCE8();
    for (;;) {
      unsigned bad = CKV(v0) | CKV(v1) | CKV(v2) | CKV(v3) |
                     CKV(v4) | CKV(v5) | CKV(v6) | CKV(v7);
      if (!bad) break;
      __builtin_amdgcn_s_sleep(1);
      LOAD8();
      FENCE8();
    }

    // ---- (5) strip tags -> swizzled h_lds[par] ----
    // WAR vs h-GEMM read(step-2, same parity): counter(step) pass => all WGs
    // past gates(step-1) ⊃ far past h-GEMM(step-2). ✓
    {
      char* hdst = (char*)&h_lds[par][0];
      PACK2(v0, 0); PACK2(v1, 1); PACK2(v2, 2); PACK2(v3, 3);
      PACK2(v4, 4); PACK2(v5, 5); PACK2(v6, 6); PACK2(v7, 7);
    }
    __syncthreads();   // S1: h_lds[par] ready (the only barrier per step)

    // ---- (5.5) x prefetch for step+2: x_lds[par] dead after S1; loads
    // overlap h-GEMM; LDS writes race-free until S1(step+1). ----
    if (step + 2 < T_) stage_x(step + 2, par);

    // ---- (6) recurrent GEMM: 4 gate chains share each A fragment ----
    {
      const char* hbm = (const char*)&h_lds[par][0];
#pragma unroll
      for (int kt = 0; kt < 16; ++kt) {
        bf16x8 a = *(const bf16x8*)(hbm + ((arow * 1024 + kt * 64 + koff) ^ swzA));
        ai = __builtin_amdgcn_mfma_f32_16x16x32_bf16(a, br[0][kt], ai, 0, 0, 0);
        af = __builtin_amdgcn_mfma_f32_16x16x32_bf16(a, br[1][kt], af, 0, 0, 0);
        ac = __builtin_amdgcn_mfma_f32_16x16x32_bf16(a, br[2][kt], ac, 0, 0, 0);
        ao = __builtin_amdgcn_mfma_f32_16x16x32_bf16(a, br[3][kt], ao, 0, 0, 0);
      }
    }

    // ---- (7) gates fully in-register (z never leaves the thread) ----
    float chat[4];
#pragma unroll
    for (int r2 = 0; r2 < 4; ++r2) {
      float ig = fminf(fmaxf(0.2f * ai[r2] + 0.5f, 0.f), 1.f);
      float fg = fminf(fmaxf(0.2f * af[r2] + 0.5f, 0.f), 1.f);
      float og = fminf(fmaxf(0.2f * ao[r2] + 0.5f, 0.f), 1.f);
      chat[r2] = fg * c_st[r2] + ig * ftanh(ac[r2]);
      float hhat = og * ftanh(chat[r2]);
      h_st[r2] = kk[r2] * hhat + (1.f - kk[r2]) * h_st[r2];
      unsigned hv = ((unsigned)f2b(h_st[r2]) << 16) | (unsigned)(step + 1);
      const unsigned* hp = h32 + (size_t)((step + 1) & 1) * BU
                         + (b0 + r0 + r2) * U_ + uw;
      asm volatile("global_store_dword %0, %1, off sc0 sc1"
                   :: "v"(hp), "v"(hv) : "memory");
    }

    // ---- (8) barrier-free hierarchical arrive — NO drain (tags cover) ----
    // LDS round delays the counter release past the h-store issue burst
    // (R9 lesson: this head start is load-bearing).
    if (lane == 0) {
      unsigned old = atomicAdd(&wgarr[step & 3], 1u);  // LDS, per-wave arrive
      if (old == 3u) {                                  // 4th wave of this WG
        wgarr[step & 3] = 0u;
        atomicAdd(cnt_g, 1u);                           // agent scope (proven)
      }
    }

    // ---- (9) off-critical-path tail (VALU + cached stores only) ----
#pragma unroll
    for (int r2 = 0; r2 < 4; ++r2) {
      c_st[r2] = kk[r2] * chat[r2] + (1.f - kk[r2]) * c_st[r2];
      out[((size_t)(b0 + r0 + r2) * T_ + step) * U_ + uw] = h_st[r2];
    }
  }
}

extern "C" void kernel_launch(void* const* d_in, const int* in_sizes, int n_in,
                              void* d_out, int out_size, void* d_ws,
                              size_t ws_size, hipStream_t stream) {
  const float* x    = (const float*)d_in[0];
  const float* h0   = (const float*)d_in[1];
  const float* c0   = (const float*)d_in[2];
  const float* t0   = (const float*)d_in[3];
  const float* kern = (const float*)d_in[4];
  const float* rker = (const float*)d_in[5];
  const float* bias = (const float*)d_in[6];
  const float* tg   = (const float*)d_in[7];
  float* out = (float*)d_out;

  char* ws = (char*)d_ws;
  unsigned short* wt = (unsigned short*)(ws + OFF_WT);
  unsigned* h32      = (unsigned*)(ws + OFF_H32);
  unsigned* cnt      = (unsigned*)(ws + OFF_CNT);

  prep_kernel<<<1024, 256, 0, stream>>>(kern, rker, h0, wt, h32, cnt);
  plstm_kernel<<<NWG, NTH, 0, stream>>>(x, h0, c0, t0, bias, tg, wt, h32,
                                        cnt, out);
}

// Round 12
// 6929.219 us; speedup vs baseline: 1.9291x; 1.8365x over previous
//
#include <hip/hip_runtime.h>
#include <hip/hip_bf16.h>
#include <math.h>

#define B_ 128
#define T_ 2048
#define D_ 256
#define U_ 512
#define G4_ 2048
#define KT_ 768            // 512 (recurrent) + 256 (input) k-rows, transposed
#define ALPHA_ 0.001f

#define NGROUP 8           // batch groups (one per XCD under round-robin)
#define GB 16              // samples per group
#define NSLICE 32          // u-slices per group
#define SU 16              // u per slice
#define NWG (NGROUP*NSLICE) // 256  (1 WG/CU, fully resident)
#define NTH 256
#define BU (B_*U_)

typedef __attribute__((ext_vector_type(8))) short bf16x8;
typedef __attribute__((ext_vector_type(4))) float f32x4;
typedef __attribute__((ext_vector_type(4))) int i32x4;
typedef __attribute__((ext_vector_type(2))) int i32x2;
typedef __attribute__((ext_vector_type(4))) unsigned short us4;

// workspace layout (bytes)
#define OFF_WT 0                        // transposed bf16 weights: 3 MiB
#define OFF_H32 (G4_*KT_*2)             // 2 tagged h buffers: 2*BU*4 = 512 KiB
#define OFF_DONE (OFF_H32 + 2*BU*4)     // done slots: 8 groups x 64 dw (256B apart)
#define DONE_DW (NGROUP*64)

__device__ __forceinline__ unsigned short f2b(float f) {
  unsigned u = __builtin_bit_cast(unsigned, f);
  u += 0x7fffu + ((u >> 16) & 1u);   // round-to-nearest-even bf16
  return (unsigned short)(u >> 16);
}

__device__ __forceinline__ float ftanh(float v) {
  v = fminf(fmaxf(v, -15.f), 15.f);
  float e = __expf(2.f * v);
  return (e - 1.f) * __builtin_amdgcn_rcpf(e + 1.f);
}

__global__ void prep_kernel(const float* __restrict__ kern,
                            const float* __restrict__ rker,
                            const float* __restrict__ h0,
                            unsigned short* __restrict__ wt,
                            unsigned* __restrict__ h32,
                            unsigned* __restrict__ done) {
  int idx = blockIdx.x * blockDim.x + threadIdx.x;
  int stride = gridDim.x * blockDim.x;
  for (int i = idx; i < G4_ * KT_; i += stride) {
    int col = i / KT_, k = i - col * KT_;
    float v = (k < U_) ? rker[(size_t)k * G4_ + col]
                       : kern[(size_t)(k - U_) * G4_ + col];
    wt[i] = f2b(v);
  }
  for (int i = idx; i < BU; i += stride) {
    h32[i] = ((unsigned)f2b(h0[i]) << 16);   // tag 0 = state entering step 0
    h32[BU + i] = 0xFFFFu;                   // impossible tag (kills stale runs)
  }
  for (int i = idx; i < DONE_DW; i += stride) done[i] = 0u;
}

// coalesced bulk h load: per instruction, 64 lanes x 16B = 1KB contiguous
#define LOAD8()                                                        \
  asm volatile(                                                        \
      "global_load_dwordx4 %0, %8, off sc0 sc1\n\t"                    \
      "global_load_dwordx4 %1, %8, off offset:1024 sc0 sc1\n\t"        \
      "global_load_dwordx4 %2, %8, off offset:2048 sc0 sc1\n\t"        \
      "global_load_dwordx4 %3, %8, off offset:3072 sc0 sc1\n\t"        \
      "global_load_dwordx4 %4, %9, off sc0 sc1\n\t"                    \
      "global_load_dwordx4 %5, %9, off offset:1024 sc0 sc1\n\t"        \
      "global_load_dwordx4 %6, %9, off offset:2048 sc0 sc1\n\t"        \
      "global_load_dwordx4 %7, %9, off offset:3072 sc0 sc1"            \
      : "=&v"(v0), "=&v"(v1), "=&v"(v2), "=&v"(v3),                    \
        "=&v"(v4), "=&v"(v5), "=&v"(v6), "=&v"(v7)                     \
      : "v"(ppoll), "v"(ppoll2));                                      \
  __builtin_amdgcn_sched_barrier(0)

#define FENCE8()                                                       \
  asm volatile("s_waitcnt vmcnt(0)"                                    \
      : "+v"(v0), "+v"(v1), "+v"(v2), "+v"(v3),                        \
        "+v"(v4), "+v"(v5), "+v"(v6), "+v"(v7));                       \
  __builtin_amdgcn_sched_barrier(0)

#define CKV(vv) ((((unsigned)(vv)[0] ^ tgv) & 0xffffu) |               \
                 (((unsigned)(vv)[1] ^ tgv) & 0xffffu) |               \
                 (((unsigned)(vv)[2] ^ tgv) & 0xffffu) |               \
                 (((unsigned)(vv)[3] ^ tgv) & 0xffffu))

#define PK(lo, hi) (int)(((unsigned)(hi) & 0xffff0000u) | ((unsigned)(lo) >> 16))

// strip tags from one 16B chunk -> 8B bf16 pair-write to swizzled LDS
// chunk k covers h[row = wave*4 + (k>>1)][u = (k&1)*256 + lane*4 .. +3]
#define PACK2(vv, k)                                                         \
  { const int r_ = 4 * wv + ((k) >> 1);                                      \
    const int ba_ = (r_ * 1024 + (((k) & 1) << 9) + 8 * ln) ^ ((r_ & 7) << 4); \
    i32x2 d_ = { PK((vv)[0], (vv)[1]), PK((vv)[2], (vv)[3]) };               \
    *(i32x2*)(hdst + ba_) = d_; }

__global__ __launch_bounds__(NTH, 1) void plstm_kernel(
    const float* __restrict__ x, const float* __restrict__ h0,
    const float* __restrict__ c0, const float* __restrict__ t0,
    const float* __restrict__ bias, const float* __restrict__ tg,
    const unsigned short* __restrict__ wt,
    unsigned* h32, unsigned* done, float* __restrict__ out) {
  const int wg = blockIdx.x;
  const int g = wg & 7, sl = wg >> 3;   // group == XCD (round-robin locality)
  const int b0 = g * GB, u0 = sl * SU;
  const int tid = threadIdx.x;
  const int wave = tid >> 6, lane = tid & 63;

  __shared__ unsigned short h_lds[2][GB * U_];   // 2 x 16 KiB, XOR-swizzled
  __shared__ unsigned short x_lds[2][GB * D_];   // 2 x 8 KiB
  __shared__ float z_lds[2][GB][68];             // 64 + pad
  __shared__ unsigned wgarr[4];                  // per-WG arrive slots

  // ---- weight fragments (transposed layout: contiguous 16B per frag) ----
  bf16x8 br[16], bx[8];
  {
    const int kr0 = (lane >> 4) * 8;
    const int col0 = wave * U_ + u0 + (lane & 15);
    const unsigned short* w0 = wt + (size_t)col0 * KT_;
#pragma unroll
    for (int kt = 0; kt < 16; ++kt) br[kt] = *(const bf16x8*)(w0 + kt * 32 + kr0);
#pragma unroll
    for (int kt = 0; kt < 8; ++kt)  bx[kt] = *(const bf16x8*)(w0 + U_ + kt * 32 + kr0);
  }
  const float bias_l = bias[wave * U_ + u0 + (lane & 15)];

  // ---- per-thread elementwise state: (sample srow, single u) ----
  const int srow = tid >> 4;
  const int j = tid & 15;
  const int bb = b0 + srow;
  const int uu = u0 + j;
  float c_st = c0[bb * U_ + uu];
  float h_st = h0[bb * U_ + uu];
  const float t_0 = t0[bb * U_ + uu];
  const float per = tg[uu];
  const float shf = tg[U_ + uu];
  const float ron = tg[2 * U_ + uu];

  const int arow = lane & 15;
  const int koff = (lane >> 4) * 16;
  const int swzA = (arow & 7) << 4;
  const int swzR = (srow & 7) << 4;
  const int wv = wave, ln = lane;

  auto stage_x = [&](int t, int buf) {
    const int f0 = j * 16;
    const float* xp = x + ((size_t)bb * T_ + t) * D_ + f0;
    char* base = (char*)&x_lds[buf][0];
#pragma unroll
    for (int q = 0; q < 4; ++q) {
      float4 v = *(const float4*)(xp + q * 4);
      us4 pk = { f2b(v.x), f2b(v.y), f2b(v.z), f2b(v.w) };
      *(us4*)(base + ((srow * 512 + (f0 + q * 4) * 2) ^ swzR)) = pk;
    }
  };

  stage_x(0, 0);
  stage_x(1, 1);
  if (tid < 4) wgarr[tid] = 0u;
  __syncthreads();   // covers prologue x staging + wgarr init

  // wave-linear bulk pointers: wave w covers group-slab bytes [w*8K,(w+1)*8K)
  const unsigned* gslab0 = h32 + (size_t)b0 * U_;
  const int poff = wave * 2048 + lane * 4;   // dwords
  // done slots: 32 per group (4B apart, 2 cache lines); consumer polls all 32
  unsigned* done_g = done + g * 64;
  const unsigned* dslot = done_g + (lane & 31);
  const unsigned* dmine = done_g + sl;

  for (int step = 0; step < T_; ++step) {
    const int par = step & 1;

    // ---- (1) per-wave done poll: all 32 producer WGs stored h(step).
    // Plain loads of 32 independent slots (2 line txns) — replaces R8's
    // 32-deep serialized atomic-RMW chain on a single address. ----
    if (step > 0) {
      const unsigned tgt = (unsigned)step;
      for (;;) {
        unsigned d;
        asm volatile("global_load_dword %0, %1, off sc0 sc1\n\t"
                     "s_waitcnt vmcnt(0)"
                     : "=v"(d) : "v"(dslot) : "memory");
        if (__all((int)(d >= tgt))) break;
        __builtin_amdgcn_s_sleep(1);
      }
    }

    // ---- (2) single fresh bulk h load, fired immediately on poll pass ----
    const unsigned* ppoll = gslab0 + (size_t)par * BU + poff;
    const unsigned* ppoll2 = ppoll + 1024;
    i32x4 v0, v1, v2, v3, v4, v5, v6, v7;
    LOAD8();

    // ---- (3) time-gate coeff + x-partial GEMM in the load RTT shadow ----
    float kk;
    {
      float xx = t_0 + (float)(step + 1) - shf;
      float ph = (xx - per * floorf(xx / per)) / per;
      kk = (ph <= 0.5f * ron) ? (2.f * ph / ron)
         : ((ph <= ron) ? (2.f - 2.f * ph / ron) : (ALPHA_ * ph));
    }
    f32x4 aa = { bias_l, bias_l, bias_l, bias_l };
    f32x4 ab = { 0.f, 0.f, 0.f, 0.f };
    {
      // x_lds[par] written post-S1(step-2); separated by S2(step-2),S1(step-1) ✓
      const char* xb = (const char*)&x_lds[par][0];
#pragma unroll
      for (int kt = 0; kt < 8; ++kt) {
        bf16x8 a = *(const bf16x8*)(xb + ((arow * 512 + kt * 64 + koff) ^ swzA));
        if (kt & 1) ab = __builtin_amdgcn_mfma_f32_16x16x32_bf16(a, bx[kt], ab, 0, 0, 0);
        else        aa = __builtin_amdgcn_mfma_f32_16x16x32_bf16(a, bx[kt], aa, 0, 0, 0);
      }
    }

    // ---- (4) validate tags; stale (done-before-h inversion) -> reload ----
    const unsigned tgv = (unsigned)step;
    FENCE8();
    for (;;) {
      unsigned bad = CKV(v0) | CKV(v1) | CKV(v2) | CKV(v3) |
                     CKV(v4) | CKV(v5) | CKV(v6) | CKV(v7);
      if (!bad) break;
      __builtin_amdgcn_s_sleep(1);
      LOAD8();
      FENCE8();
    }

    // ---- (5) strip tags -> swizzled h_lds[par] ----
    // WAR vs h-GEMM read(step-2, same parity): done(step) pass => all WGs
    // past gates(step-1) ⊃ far past h-GEMM(step-2). ✓
    {
      char* hdst = (char*)&h_lds[par][0];
      PACK2(v0, 0); PACK2(v1, 1); PACK2(v2, 2); PACK2(v3, 3);
      PACK2(v4, 4); PACK2(v5, 5); PACK2(v6, 6); PACK2(v7, 7);
    }
    __syncthreads();   // S1: h_lds[par] ready

    // ---- (5.5) x prefetch for step+2: x_lds[par] dead after S1 (all waves'
    // x-GEMM reads precede S1); loads overlap h-GEMM below; LDS writes are
    // ordered before the step+2 reads by S1(step+1). Keeps the x-load vmcnt
    // away from next step's poll entry. ----
    if (step + 2 < T_) stage_x(step + 2, par);

    // ---- (6) recurrent GEMM (2 interleaved acc chains) ----
    {
      const char* hbm = (const char*)&h_lds[par][0];
#pragma unroll
      for (int kt = 0; kt < 16; ++kt) {
        bf16x8 a = *(const bf16x8*)(hbm + ((arow * 1024 + kt * 64 + koff) ^ swzA));
        if (kt & 1) ab = __builtin_amdgcn_mfma_f32_16x16x32_bf16(a, br[kt], ab, 0, 0, 0);
        else        aa = __builtin_amdgcn_mfma_f32_16x16x32_bf16(a, br[kt], aa, 0, 0, 0);
      }
    }
    const f32x4 acc = aa + ab;

    // ---- (7) z exchange (C/D: col=lane&15, row=(lane>>4)*4+r) ----
#pragma unroll
    for (int r2 = 0; r2 < 4; ++r2)
      z_lds[par][(lane >> 4) * 4 + r2][wave * 16 + (lane & 15)] = acc[r2];
    __syncthreads();   // S2: z ready

    // ---- (8) gates: h path first -> tagged store ASAP, arrive, then tail ----
    float chat;
    {
      const float* zr = &z_lds[par][srow][0];
      const float zi = zr[j], zf = zr[16 + j], zc = zr[32 + j], zo = zr[48 + j];
      float ig = fminf(fmaxf(0.2f * zi + 0.5f, 0.f), 1.f);
      float fg = fminf(fmaxf(0.2f * zf + 0.5f, 0.f), 1.f);
      float og = fminf(fmaxf(0.2f * zo + 0.5f, 0.f), 1.f);
      chat = fg * c_st + ig * ftanh(zc);
      float hhat = og * ftanh(chat);
      h_st = kk * hhat + (1.f - kk) * h_st;
      unsigned hv = ((unsigned)f2b(h_st) << 16) | (unsigned)(step + 1);
      const unsigned* hp = h32 + (size_t)((step + 1) & 1) * BU + bb * U_ + uu;
      asm volatile("global_store_dword %0, %1, off sc0 sc1"
                   :: "v"(hp), "v"(hv) : "memory");
    }

    // ---- (9) barrier-free hierarchical arrive — NO drain, NO atomic RMW.
    // LDS round gives the h-stores a visibility head start (R9 lesson) before
    // the 4th wave's lane0 plain-stores the done slot. Tags absorb the rare
    // done-before-h inversion (R8-proven). ----
    if (lane == 0) {
      unsigned old = atomicAdd(&wgarr[step & 3], 1u);  // LDS, per-wave arrive
      if (old == 3u) {                                  // 4th wave of this WG
        wgarr[step & 3] = 0u;
        unsigned dv = (unsigned)(step + 1);
        asm volatile("global_store_dword %0, %1, off sc0 sc1"
                     :: "v"(dmine), "v"(dv) : "memory");
      }
    }

    // ---- (10) off-critical-path tail (VALU + cached store only) ----
    c_st = kk * chat + (1.f - kk) * c_st;
    out[((size_t)bb * T_ + step) * U_ + uu] = h_st;
  }
}

extern "C" void kernel_launch(void* const* d_in, const int* in_sizes, int n_in,
                              void* d_out, int out_size, void* d_ws,
                              size_t ws_size, hipStream_t stream) {
  const float* x    = (const float*)d_in[0];
  const float* h0   = (const float*)d_in[1];
  const float* c0   = (const float*)d_in[2];
  const float* t0   = (const float*)d_in[3];
  const float* kern = (const float*)d_in[4];
  const float* rker = (const float*)d_in[5];
  const float* bias = (const float*)d_in[6];
  const float* tg   = (const float*)d_in[7];
  float* out = (float*)d_out;

  char* ws = (char*)d_ws;
  unsigned short* wt = (unsigned short*)(ws + OFF_WT);
  unsigned* h32      = (unsigned*)(ws + OFF_H32);
  unsigned* done     = (unsigned*)(ws + OFF_DONE);

  prep_kernel<<<1024, 256, 0, stream>>>(kern, rker, h0, wt, h32, done);
  plstm_kernel<<<NWG, NTH, 0, stream>>>(x, h0, c0, t0, bias, tg, wt, h32,
                                        done, out);
}

// Round 13
// 6258.242 us; speedup vs baseline: 2.1359x; 1.1072x over previous
//
#include <hip/hip_runtime.h>
#include <hip/hip_bf16.h>
#include <math.h>

#define B_ 128
#define T_ 2048
#define D_ 256
#define U_ 512
#define G4_ 2048
#define KT_ 768            // 512 (recurrent) + 256 (input) k-rows, transposed
#define ALPHA_ 0.001f

#define NGROUP 8           // batch groups (one per XCD under round-robin)
#define GB 16              // samples per group
#define NSLICE 32          // u-slices per group
#define SU 16              // u per slice
#define NWG (NGROUP*NSLICE) // 256  (1 WG/CU, fully resident)
#define NTH 256
#define BU (B_*U_)

typedef __attribute__((ext_vector_type(8))) short bf16x8;
typedef __attribute__((ext_vector_type(4))) float f32x4;
typedef __attribute__((ext_vector_type(4))) int i32x4;
typedef __attribute__((ext_vector_type(2))) int i32x2;
typedef __attribute__((ext_vector_type(4))) unsigned short us4;

// workspace layout (bytes)
#define OFF_WT 0                        // transposed bf16 weights: 3 MiB
#define OFF_H32 (G4_*KT_*2)             // 2 tagged h buffers: 2*BU*4 = 512 KiB

__device__ __forceinline__ unsigned short f2b(float f) {
  unsigned u = __builtin_bit_cast(unsigned, f);
  u += 0x7fffu + ((u >> 16) & 1u);   // round-to-nearest-even bf16
  return (unsigned short)(u >> 16);
}

__device__ __forceinline__ float ftanh(float v) {
  v = fminf(fmaxf(v, -15.f), 15.f);
  float e = __expf(2.f * v);
  return (e - 1.f) * __builtin_amdgcn_rcpf(e + 1.f);
}

__global__ void prep_kernel(const float* __restrict__ kern,
                            const float* __restrict__ rker,
                            const float* __restrict__ h0,
                            unsigned short* __restrict__ wt,
                            unsigned* __restrict__ h32) {
  int idx = blockIdx.x * blockDim.x + threadIdx.x;
  int stride = gridDim.x * blockDim.x;
  for (int i = idx; i < G4_ * KT_; i += stride) {
    int col = i / KT_, k = i - col * KT_;
    float v = (k < U_) ? rker[(size_t)k * G4_ + col]
                       : kern[(size_t)(k - U_) * G4_ + col];
    wt[i] = f2b(v);
  }
  for (int i = idx; i < BU; i += stride) {
    h32[i] = ((unsigned)f2b(h0[i]) << 16);   // tag 0 = state entering step 0
    h32[BU + i] = 0xFFFFu;                   // impossible tag (kills stale runs)
  }
}

// coalesced bulk h load: per instruction, 64 lanes x 16B = 1KB contiguous
#define LOAD8()                                                        \
  asm volatile(                                                        \
      "global_load_dwordx4 %0, %8, off sc0 sc1\n\t"                    \
      "global_load_dwordx4 %1, %8, off offset:1024 sc0 sc1\n\t"        \
      "global_load_dwordx4 %2, %8, off offset:2048 sc0 sc1\n\t"        \
      "global_load_dwordx4 %3, %8, off offset:3072 sc0 sc1\n\t"        \
      "global_load_dwordx4 %4, %9, off sc0 sc1\n\t"                    \
      "global_load_dwordx4 %5, %9, off offset:1024 sc0 sc1\n\t"        \
      "global_load_dwordx4 %6, %9, off offset:2048 sc0 sc1\n\t"        \
      "global_load_dwordx4 %7, %9, off offset:3072 sc0 sc1"            \
      : "=&v"(v0), "=&v"(v1), "=&v"(v2), "=&v"(v3),                    \
        "=&v"(v4), "=&v"(v5), "=&v"(v6), "=&v"(v7)                     \
      : "v"(ppoll), "v"(ppoll2));                                      \
  __builtin_amdgcn_sched_barrier(0)

// vmcnt(0): bulk regs AND sentinel regs stay bound until every in-flight
// load (incl. stray poll) has landed -> no phys-reg reuse hazard (R9 lesson)
#define FENCE8()                                                       \
  asm volatile("s_waitcnt vmcnt(0)"                                    \
      : "+v"(v0), "+v"(v1), "+v"(v2), "+v"(v3),                        \
        "+v"(v4), "+v"(v5), "+v"(v6), "+v"(v7),                        \
        "+v"(dA0), "+v"(dA1), "+v"(dB0), "+v"(dB1));                   \
  __builtin_amdgcn_sched_barrier(0)

// sentinel pair: lane's first consumed dword of producers lane>>2 and
// 16+(lane>>2); across the wave all 32 producers are covered. 1KB-span
// coalesced per instruction.
#define POLL2(a, b)                                                    \
  asm volatile(                                                        \
      "global_load_dword %0, %2, off sc0 sc1\n\t"                      \
      "global_load_dword %1, %3, off sc0 sc1"                          \
      : "=&v"(a), "=&v"(b) : "v"(s0p), "v"(s1p));                      \
  __builtin_amdgcn_sched_barrier(0)

// wait for the OLDER pair of the two in flight (loads retire in issue order)
#define WAITP()                                                        \
  asm volatile("s_waitcnt vmcnt(2)"                                    \
      : "+v"(dA0), "+v"(dA1), "+v"(dB0), "+v"(dB1));                   \
  __builtin_amdgcn_sched_barrier(0)

#define CKV(vv) ((((unsigned)(vv)[0] ^ tgv) & 0xffffu) |               \
                 (((unsigned)(vv)[1] ^ tgv) & 0xffffu) |               \
                 (((unsigned)(vv)[2] ^ tgv) & 0xffffu) |               \
                 (((unsigned)(vv)[3] ^ tgv) & 0xffffu))

#define PK(lo, hi) (int)(((unsigned)(hi) & 0xffff0000u) | ((unsigned)(lo) >> 16))

// strip tags from one 16B chunk -> 8B bf16 pair-write to swizzled LDS
// chunk k covers h[row = wave*4 + (k>>1)][u = (k&1)*256 + lane*4 .. +3]
#define PACK2(vv, k)                                                         \
  { const int r_ = 4 * wv + ((k) >> 1);                                      \
    const int ba_ = (r_ * 1024 + (((k) & 1) << 9) + 8 * ln) ^ ((r_ & 7) << 4); \
    i32x2 d_ = { PK((vv)[0], (vv)[1]), PK((vv)[2], (vv)[3]) };               \
    *(i32x2*)(hdst + ba_) = d_; }

__global__ __launch_bounds__(NTH, 1) void plstm_kernel(
    const float* __restrict__ x, const float* __restrict__ h0,
    const float* __restrict__ c0, const float* __restrict__ t0,
    const float* __restrict__ bias, const float* __restrict__ tg,
    const unsigned short* __restrict__ wt,
    unsigned* h32, float* __restrict__ out) {
  const int wg = blockIdx.x;
  const int g = wg & 7, sl = wg >> 3;   // group == XCD (round-robin locality)
  const int b0 = g * GB, u0 = sl * SU;
  const int tid = threadIdx.x;
  const int wave = tid >> 6, lane = tid & 63;

  __shared__ unsigned short h_lds[2][GB * U_];   // 2 x 16 KiB, XOR-swizzled
  __shared__ unsigned short x_lds[2][GB * D_];   // 2 x 8 KiB
  __shared__ float z_lds[2][GB][68];             // 64 + pad

  // ---- weight fragments (transposed layout: contiguous 16B per frag) ----
  bf16x8 br[16], bx[8];
  {
    const int kr0 = (lane >> 4) * 8;
    const int col0 = wave * U_ + u0 + (lane & 15);
    const unsigned short* w0 = wt + (size_t)col0 * KT_;
#pragma unroll
    for (int kt = 0; kt < 16; ++kt) br[kt] = *(const bf16x8*)(w0 + kt * 32 + kr0);
#pragma unroll
    for (int kt = 0; kt < 8; ++kt)  bx[kt] = *(const bf16x8*)(w0 + U_ + kt * 32 + kr0);
  }
  const float bias_l = bias[wave * U_ + u0 + (lane & 15)];

  // ---- per-thread elementwise state: (sample srow, single u) ----
  const int srow = tid >> 4;
  const int j = tid & 15;
  const int bb = b0 + srow;
  const int uu = u0 + j;
  float c_st = c0[bb * U_ + uu];
  float h_st = h0[bb * U_ + uu];
  const float t_0 = t0[bb * U_ + uu];
  const float per = tg[uu];
  const float shf = tg[U_ + uu];
  const float ron = tg[2 * U_ + uu];

  const int arow = lane & 15;
  const int koff = (lane >> 4) * 16;
  const int swzA = (arow & 7) << 4;
  const int swzR = (srow & 7) << 4;
  const int wv = wave, ln = lane;

  auto stage_x = [&](int t, int buf) {
    const int f0 = j * 16;
    const float* xp = x + ((size_t)bb * T_ + t) * D_ + f0;
    char* base = (char*)&x_lds[buf][0];
#pragma unroll
    for (int q = 0; q < 4; ++q) {
      float4 v = *(const float4*)(xp + q * 4);
      us4 pk = { f2b(v.x), f2b(v.y), f2b(v.z), f2b(v.w) };
      *(us4*)(base + ((srow * 512 + (f0 + q * 4) * 2) ^ swzR)) = pk;
    }
  };

  stage_x(0, 0);
  stage_x(1, 1);
  __syncthreads();   // covers prologue x staging

  // wave-linear bulk pointers: wave w covers group-slab bytes [w*8K,(w+1)*8K)
  const unsigned* gslab0 = h32 + (size_t)b0 * U_;
  const int poff = wave * 2048 + lane * 4;   // dwords

  unsigned dA0 = 0, dA1 = 0, dB0 = 0, dB1 = 0;   // sentinel poll regs

  for (int step = 0; step < T_; ++step) {
    const int par = step & 1;
    const unsigned* ppoll = gslab0 + (size_t)par * BU + poff;
    const unsigned* ppoll2 = ppoll + 1024;

    // ---- (1) sentinel poll: the h data itself is the readiness flag.
    // Drain own stores once (overlaps waiting on other producers), then
    // staggered 2-deep pair polling -> sampling period ~= RTT/2. ----
    if (step > 0) {
      asm volatile("s_waitcnt vmcnt(0)" ::: "memory");
      const unsigned* s0p = ppoll;          // row 4w, u = 4*lane
      const unsigned* s1p = ppoll + 256;    // row 4w, u = 256 + 4*lane
      const unsigned tgp = (unsigned)step;
      POLL2(dA0, dA1);
      POLL2(dB0, dB1);
      for (;;) {
        WAITP();   // A pair landed
        if (__all((int)((((dA0 ^ tgp) | (dA1 ^ tgp)) & 0xffffu) == 0))) break;
        POLL2(dA0, dA1);
        WAITP();   // B pair landed
        if (__all((int)((((dB0 ^ tgp) | (dB1 ^ tgp)) & 0xffffu) == 0))) break;
        POLL2(dB0, dB1);
      }
      // up to 2 poll loads remain in flight; dA*/dB* stay bound via FENCE8
    }

    // ---- (2) single fresh bulk h load, fired immediately on poll pass ----
    i32x4 v0, v1, v2, v3, v4, v5, v6, v7;
    LOAD8();

    // ---- (3) time-gate coeff + x-partial GEMM in the load RTT shadow ----
    float kk;
    {
      float xx = t_0 + (float)(step + 1) - shf;
      float ph = (xx - per * floorf(xx / per)) / per;
      kk = (ph <= 0.5f * ron) ? (2.f * ph / ron)
         : ((ph <= ron) ? (2.f - 2.f * ph / ron) : (ALPHA_ * ph));
    }
    f32x4 aa = { bias_l, bias_l, bias_l, bias_l };
    f32x4 ab = { 0.f, 0.f, 0.f, 0.f };
    {
      // x_lds[par] written post-S1(step-2); separated by S2(step-2),S1(step-1) ✓
      const char* xb = (const char*)&x_lds[par][0];
#pragma unroll
      for (int kt = 0; kt < 8; ++kt) {
        bf16x8 a = *(const bf16x8*)(xb + ((arow * 512 + kt * 64 + koff) ^ swzA));
        if (kt & 1) ab = __builtin_amdgcn_mfma_f32_16x16x32_bf16(a, bx[kt], ab, 0, 0, 0);
        else        aa = __builtin_amdgcn_mfma_f32_16x16x32_bf16(a, bx[kt], aa, 0, 0, 0);
      }
    }

    // ---- (4) validate tags; stale (within-burst reorder) -> reload ----
    const unsigned tgv = (unsigned)step;
    FENCE8();
    for (;;) {
      unsigned bad = CKV(v0) | CKV(v1) | CKV(v2) | CKV(v3) |
                     CKV(v4) | CKV(v5) | CKV(v6) | CKV(v7);
      if (!bad) break;
      __builtin_amdgcn_s_sleep(1);
      LOAD8();
      FENCE8();
    }

    // ---- (5) strip tags -> swizzled h_lds[par] ----
    // WAR vs h-GEMM read(step-2, same parity): sentinel(step) pass => all
    // producers past gates(step-1) ⊃ far past h-GEMM(step-2). ✓
    {
      char* hdst = (char*)&h_lds[par][0];
      PACK2(v0, 0); PACK2(v1, 1); PACK2(v2, 2); PACK2(v3, 3);
      PACK2(v4, 4); PACK2(v5, 5); PACK2(v6, 6); PACK2(v7, 7);
    }
    __syncthreads();   // S1: h_lds[par] ready

    // ---- (5.5) x prefetch for step+2: x_lds[par] dead after S1; loads
    // overlap h-GEMM below; ordered before step+2 reads by S1(step+1);
    // keeps the x-load vmcnt away from next step's poll entry drain. ----
    if (step + 2 < T_) stage_x(step + 2, par);

    // ---- (6) recurrent GEMM (2 interleaved acc chains) ----
    {
      const char* hbm = (const char*)&h_lds[par][0];
#pragma unroll
      for (int kt = 0; kt < 16; ++kt) {
        bf16x8 a = *(const bf16x8*)(hbm + ((arow * 1024 + kt * 64 + koff) ^ swzA));
        if (kt & 1) ab = __builtin_amdgcn_mfma_f32_16x16x32_bf16(a, br[kt], ab, 0, 0, 0);
        else        aa = __builtin_amdgcn_mfma_f32_16x16x32_bf16(a, br[kt], aa, 0, 0, 0);
      }
    }
    const f32x4 acc = aa + ab;

    // ---- (7) z exchange (C/D: col=lane&15, row=(lane>>4)*4+r) ----
#pragma unroll
    for (int r2 = 0; r2 < 4; ++r2)
      z_lds[par][(lane >> 4) * 4 + r2][wave * 16 + (lane & 15)] = acc[r2];
    __syncthreads();   // S2: z ready

    // ---- (8) gates: h path -> tagged store (the store IS the signal) ----
    float chat;
    {
      const float* zr = &z_lds[par][srow][0];
      const float zi = zr[j], zf = zr[16 + j], zc = zr[32 + j], zo = zr[48 + j];
      float ig = fminf(fmaxf(0.2f * zi + 0.5f, 0.f), 1.f);
      float fg = fminf(fmaxf(0.2f * zf + 0.5f, 0.f), 1.f);
      float og = fminf(fmaxf(0.2f * zo + 0.5f, 0.f), 1.f);
      chat = fg * c_st + ig * ftanh(zc);
      float hhat = og * ftanh(chat);
      h_st = kk * hhat + (1.f - kk) * h_st;
      unsigned hv = ((unsigned)f2b(h_st) << 16) | (unsigned)(step + 1);
      const unsigned* hp = h32 + (size_t)((step + 1) & 1) * BU + bb * U_ + uu;
      asm volatile("global_store_dword %0, %1, off sc0 sc1"
                   :: "v"(hp), "v"(hv) : "memory");
    }

    // ---- (9) off-critical-path tail (VALU + cached store only) ----
    c_st = kk * chat + (1.f - kk) * c_st;
    out[((size_t)bb * T_ + step) * U_ + uu] = h_st;
  }
}

extern "C" void kernel_launch(void* const* d_in, const int* in_sizes, int n_in,
                              void* d_out, int out_size, void* d_ws,
                              size_t ws_size, hipStream_t stream) {
  const float* x    = (const float*)d_in[0];
  const float* h0   = (const float*)d_in[1];
  const float* c0   = (const float*)d_in[2];
  const float* t0   = (const float*)d_in[3];
  const float* kern = (const float*)d_in[4];
  const float* rker = (const float*)d_in[5];
  const float* bias = (const float*)d_in[6];
  const float* tg   = (const float*)d_in[7];
  float* out = (float*)d_out;

  char* ws = (char*)d_ws;
  unsigned short* wt = (unsigned short*)(ws + OFF_WT);
  unsigned* h32      = (unsigned*)(ws + OFF_H32);

  prep_kernel<<<1024, 256, 0, stream>>>(kern, rker, h0, wt, h32);
  plstm_kernel<<<NWG, NTH, 0, stream>>>(x, h0, c0, t0, bias, tg, wt, h32, out);
}